// Round 4
// baseline (5068.613 us; speedup 1.0000x reference)
//
#include <hip/hip_runtime.h>
#include <hip/hip_bf16.h>

#define BB 32
#define CC 64
#define NN 307
#define TT 24
#define CO 192
#define NT (NN*TT)   // 7368

using bf16 = __hip_bfloat16;

// fp32 weight-arena offsets (element = float)
#define OFF_ln_g   0
#define OFF_ln_b   24
#define OFF_res_W  48
#define OFF_res_b  12336
#define OFF_ca_W1  12528
#define OFF_ca_W2  12552
#define OFF_ca_W3  19920
#define OFF_cc_W   20227
#define OFF_cc_b   24323
#define OFF_ta_W1  24387
#define OFF_ta_W2  24694
#define OFF_ta_W3  44342
#define OFF_tc_W0  44406
#define OFF_tc_b0  52598
#define OFF_tc_W1  52662
#define OFF_tc_b1  60854
#define OFF_ga_W1  60918
#define OFF_ga_W2  60942
#define OFF_ga_W3  62478
#define OFF_g_W    62542
#define W_TOTAL    66638

__device__ __forceinline__ float xload(const void* p, size_t i, int f) {
  return f ? ((const float*)p)[i] : __bfloat162float(((const bf16*)p)[i]);
}
__device__ __forceinline__ void ostore(void* p, size_t i, float v, int f) {
  if (f) ((float*)p)[i] = v; else ((bf16*)p)[i] = __float2bfloat16(v);
}
__device__ __forceinline__ float oload(const void* p, size_t i, int f) {
  return f ? ((const float*)p)[i] : __bfloat162float(((const bf16*)p)[i]);
}

// Keep the template's symbol in case the loader expects it.
__global__ void MEAM_44787918963464_kernel() {}

// ---- 0a. probe input float dtype from ln_g (all ones)
__global__ __launch_bounds__(256) void k_probe(const void* lng_raw, int* flag) {
  if (threadIdx.x == 0 && blockIdx.x == 0) {
    unsigned w = *(const unsigned*)lng_raw;
    *flag = (w == 0x3F800000u) ? 1 : 0;   // 1 = float32 inputs, 0 = bf16
  }
}

// ---- 0b. convert all small weights to fp32 arena
__global__ __launch_bounds__(256) void k_cvt_w(
    const void* p0, const void* p1, const void* p2, const void* p3,
    const void* p4, const void* p5, const void* p6, const void* p7,
    const void* p8, const void* p9, const void* p10, const void* p11,
    const void* p12, const void* p13, const void* p14, const void* p15,
    const void* p16, const void* p17, const void* p18, const void* p19,
    const int* flagp, float* dst) {
  int i = blockIdx.x*256 + threadIdx.x;
  if (i >= W_TOTAL) return;
  const void* ps[20] = {p0,p1,p2,p3,p4,p5,p6,p7,p8,p9,p10,p11,p12,p13,p14,p15,p16,p17,p18,p19};
  const int sz[20] = {24,24,12288,192,24,7368,307,4096,64,307,19648,64,8192,64,8192,64,24,1536,64,4096};
  int f = *flagp;
  int s = 0, base = 0;
  while (i >= base + sz[s]) { base += sz[s]; s++; }
  dst[i] = f ? ((const float*)ps[s])[i-base]
             : __bfloat162float(((const bf16*)ps[s])[i-base]);
}

// ---- 0c. diagnostic fill: out = 1.0 everywhere (overwritten by real pipeline)
__global__ __launch_bounds__(256) void k_fill(void* out, int n, const int* flagp) {
  int i = blockIdx.x*256 + threadIdx.x;
  int f = *flagp;
  if (i < n) ostore(out, i, 1.0f, f);
}

// ---- 1. LN stats per row (b,c,n): mu, rs; s1=sum_t h*caW1, s2=sum_t h*gaW1
__global__ __launch_bounds__(256) void k_ln(const void* __restrict__ x, const int* flagp,
    const float* __restrict__ W,
    float* __restrict__ mu_o, float* __restrict__ rs_o,
    float* __restrict__ xw1c, float* __restrict__ xw1g) {
  int r = blockIdx.x*256 + threadIdx.x;     // (b*C+c)*N + n
  if (r >= BB*CC*NN) return;
  int f = *flagp;
  const float* lng  = W + OFF_ln_g;
  const float* lnb  = W + OFF_ln_b;
  const float* caW1 = W + OFF_ca_W1;
  const float* gaW1 = W + OFF_ga_W1;
  float v[TT];
  float mu = 0.f;
  for (int t=0;t<TT;t++){ v[t] = xload(x, (size_t)r*TT+t, f); mu += v[t]; }
  mu *= (1.f/TT);
  float var = 0.f;
  for (int t=0;t<TT;t++){ float d=v[t]-mu; var += d*d; }
  var *= (1.f/TT);
  float rs = rsqrtf(var + 1e-5f);
  float s1=0.f, s2=0.f;
  for (int t=0;t<TT;t++){
    float hv = (v[t]-mu)*rs*lng[t] + lnb[t];
    s1 += hv*caW1[t];
    s2 += hv*gaW1[t];
  }
  mu_o[r]=mu; rs_o[r]=rs; xw1c[r]=s1; xw1g[r]=s2;
}

// ---- 2. per (b,c,t): lhs_c, rhs_c, xW1_t (reduce over n)
__global__ __launch_bounds__(256) void k_prep_ct(const void* __restrict__ x, const int* flagp,
    const float* __restrict__ mu_a, const float* __restrict__ rs_a,
    const float* __restrict__ W, const float* __restrict__ xw1c,
    float* __restrict__ lhsc, float* __restrict__ rhsc, float* __restrict__ xw1t) {
  int i = blockIdx.x*256 + threadIdx.x;     // (b*C+c)*T + t
  if (i >= BB*CC*TT) return;
  int f = *flagp;
  const float* lng  = W + OFF_ln_g;
  const float* lnb  = W + OFF_ln_b;
  const float* caW2 = W + OFF_ca_W2;
  const float* caW3 = W + OFF_ca_W3;
  const float* taW1 = W + OFF_ta_W1;
  int t = i % TT; int bc = i / TT;
  float gt = lng[t], bt = lnb[t];
  float l=0.f, rr=0.f, xt=0.f;
  for (int n=0;n<NN;n++){
    int row = bc*NN + n;
    float hv = (xload(x, (size_t)row*TT+t, f) - mu_a[row]) * rs_a[row] * gt + bt;
    l  += xw1c[row]*caW2[n*TT+t];
    rr += caW3[n]*hv;
    xt += taW1[n]*hv;
  }
  lhsc[i]=l; rhsc[i]=rr; xw1t[i]=xt;
}

// ---- 3. per (b,n,t): rhs_t, rhs_g, lhs_g (reduce over c)
__global__ __launch_bounds__(256) void k_prep_bn(const void* __restrict__ x, const int* flagp,
    const float* __restrict__ mu_a, const float* __restrict__ rs_a,
    const float* __restrict__ W, const float* __restrict__ xw1g,
    float* __restrict__ rhst, float* __restrict__ rhsg, float* __restrict__ lhsg) {
  int i = blockIdx.x*256 + threadIdx.x;     // (b*N+n)*T + t
  if (i >= BB*NN*TT) return;
  int f = *flagp;
  const float* lng  = W + OFF_ln_g;
  const float* lnb  = W + OFF_ln_b;
  const float* taW3 = W + OFF_ta_W3;
  const float* gaW3 = W + OFF_ga_W3;
  const float* gaW2 = W + OFF_ga_W2;
  int t = i % TT; int n = (i/TT)%NN; int b = i/(NN*TT);
  float gt = lng[t], bt = lnb[t];
  float a=0.f,c2=0.f,d=0.f;
  for (int c=0;c<CC;c++){
    int row = (b*CC+c)*NN + n;
    float hv = (xload(x, (size_t)row*TT+t, f) - mu_a[row]) * rs_a[row] * gt + bt;
    a  += taW3[c]*hv;
    c2 += gaW3[c]*hv;
    d  += xw1g[row]*gaW2[c*TT+t];
  }
  rhst[i]=a; rhsg[i]=c2; lhsg[i]=d;
}

// ---- 4. lhs_t[b,t,n] = sum_c xW1_t[b,c,t]*taW2[c,n]
__global__ __launch_bounds__(256) void k_lhs_t(const float* __restrict__ xw1t,
    const float* __restrict__ W, float* __restrict__ lhst) {
  int i = blockIdx.x*256 + threadIdx.x;     // (b*T+t)*N + n
  if (i >= BB*TT*NN) return;
  const float* taW2 = W + OFF_ta_W2;
  int n = i % NN; int t = (i/NN)%TT; int b = i/(TT*NN);
  float acc=0.f;
  for (int c=0;c<CC;c++)
    acc += xw1t[(b*CC+c)*TT+t]*taW2[c*NN+n];
  lhst[i]=acc;
}

// ---- 5. channel attention softmax folded with cc_W -> Mc[o][d]
__global__ __launch_bounds__(256) void k_att_c(const float* __restrict__ lhsc,
    const float* __restrict__ rhsc, const float* __restrict__ W,
    float* __restrict__ Mc) {
  int b = blockIdx.x; int tid = threadIdx.x;
  const float* ccW = W + OFF_cc_W;
  __shared__ float lc[CC*TT], rc[CC*TT], sc[CC*(CC+1)];
  for (int e=tid;e<CC*TT;e+=256){
    lc[e]=lhsc[b*CC*TT+e];
    rc[e]=rhsc[b*CC*TT+e];
  }
  __syncthreads();
  for (int e=tid;e<CC*CC;e+=256){
    int c=e>>6, d=e&63; float s=0.f;
    for (int t=0;t<TT;t++) s += lc[c*TT+t]*rc[d*TT+t];
    sc[c*(CC+1)+d]=s;
  }
  __syncthreads();
  if (tid<CC){
    float mx=-1e30f;
    for (int d=0;d<CC;d++) mx=fmaxf(mx, sc[tid*(CC+1)+d]);
    float sum=0.f;
    for (int d=0;d<CC;d++){ float e2=__expf(sc[tid*(CC+1)+d]-mx); sc[tid*(CC+1)+d]=e2; sum+=e2; }
    float inv=1.f/sum;
    for (int d=0;d<CC;d++) sc[tid*(CC+1)+d]*=inv;
  }
  __syncthreads();
  for (int e=tid;e<CC*CC;e+=256){
    int o=e>>6, d=e&63; float acc=0.f;
    for (int c=0;c<CC;c++) acc += ccW[o*CC+c]*sc[c*(CC+1)+d];
    Mc[b*CC*CC+e]=acc;
  }
}

// ---- 6. temporal attention 24x24 softmax
__global__ __launch_bounds__(256) void k_att_t(const float* __restrict__ lhst,
    const float* __restrict__ rhst, float* __restrict__ attt) {
  int b=blockIdx.x, tid=threadIdx.x;
  __shared__ float sc[TT*TT];
  for (int e=tid;e<TT*TT;e+=256){
    int t=e/TT, s=e%TT;
    float acc=0.f;
    for (int n=0;n<NN;n++)
      acc += lhst[(b*TT+t)*NN+n]*rhst[(b*NN+n)*TT+s];
    sc[e]=acc;
  }
  __syncthreads();
  if (tid < TT){
    float mx=-1e30f;
    for (int s=0;s<TT;s++) mx=fmaxf(mx,sc[tid*TT+s]);
    float sum=0.f;
    for (int s=0;s<TT;s++){ float e=__expf(sc[tid*TT+s]-mx); sc[tid*TT+s]=e; sum+=e; }
    float inv=1.f/sum;
    for (int s=0;s<TT;s++) attt[b*TT*TT + tid*TT + s]=sc[tid*TT+s]*inv;
  }
}

// ---- 7. c-branch: out rows 0..63 = Mc @ h + cc_b
__global__ __launch_bounds__(256) void k_cmix(const float* __restrict__ Mc,
    const void* __restrict__ x, const int* flagp,
    const float* __restrict__ mu_a, const float* __restrict__ rs_a,
    const float* __restrict__ W, void* __restrict__ out) {
  int jt=blockIdx.x, b=blockIdx.y, tid=threadIdx.x;
  int f = *flagp;
  int j0=jt*64;
  const float* lng = W + OFF_ln_g;
  const float* lnb = W + OFF_ln_b;
  const float* ccb = W + OFF_cc_b;
  __shared__ float Ms[CC*64];    // [d][o]
  __shared__ float Hs[CC*64];    // [d][j]
  for (int e=tid;e<CC*64;e+=256){
    int o=e&63, d=e>>6;
    Ms[e]=Mc[b*CC*CC + o*CC + d];
  }
  for (int e=tid;e<CC*64;e+=256){
    int d=e>>6, j=e&63; int jj=j0+j;
    float hv = 0.f;
    if (jj<NT){
      int n = jj/TT, t = jj%TT;
      int row = (b*CC+d)*NN + n;
      hv = (xload(x, (size_t)(b*CC+d)*NT + jj, f) - mu_a[row]) * rs_a[row] * lng[t] + lnb[t];
    }
    Hs[e]=hv;
  }
  __syncthreads();
  int ti=tid&15, tj=tid>>4;
  float acc[4][4]={};
  for (int d=0;d<CC;d++){
    float4 a4=*(const float4*)&Ms[d*64+ti*4];
    float4 b4=*(const float4*)&Hs[d*64+tj*4];
    float av[4]={a4.x,a4.y,a4.z,a4.w};
    float bv[4]={b4.x,b4.y,b4.z,b4.w};
    for (int i=0;i<4;i++)
      for (int j=0;j<4;j++) acc[i][j]+=av[i]*bv[j];
  }
  for (int i=0;i<4;i++){
    int o=ti*4+i; float bias=ccb[o];
    for (int j=0;j<4;j++){
      int jj=j0+tj*4+j;
      if (jj<NT)
        ostore(out, ((size_t)b*CO+o)*NT+jj, acc[i][j]+bias, f);
    }
  }
}

// ---- 8. g-branch fully fused (softmax over m + apply + gW mix); rows 128..191
__global__ __launch_bounds__(256) void k_graph(const float* __restrict__ lhsg,
    const float* __restrict__ rhsg, const int* __restrict__ adj,
    const void* __restrict__ x, const int* flagp,
    const float* __restrict__ mu_a, const float* __restrict__ rs_a,
    const float* __restrict__ W, void* __restrict__ out) {
  int n = blockIdx.x, b = blockIdx.y, tid = threadIdx.x;
  int f = *flagp;
  const float* lng = W + OFF_ln_g;
  const float* lnb = W + OFF_ln_b;
  const float* gW  = W + OFF_g_W;
  __shared__ float ls[TT];
  __shared__ float sv[NN];
  __shared__ float red[256];
  __shared__ float wl[NN];
  __shared__ int   ml[NN];
  __shared__ int   cnt;
  __shared__ float z[CC*TT];
  __shared__ float Gs[CC*CC];
  __shared__ float gs[TT], bs[TT];
  if (tid < TT){
    ls[tid] = lhsg[(b*NN+n)*TT + tid];
    gs[tid] = lng[tid]; bs[tid] = lnb[tid];
  }
  for (int e=tid;e<CC*CC;e+=256) Gs[e]=gW[e];
  __syncthreads();
  float lmax = -1e30f;
  for (int m=tid;m<NN;m+=256){
    float s = -1e30f;
    if (adj[n*NN+m] > 0){
      const float* rr = rhsg + ((size_t)b*NN+m)*TT;
      float acc=0.f;
      for (int t=0;t<TT;t++) acc += ls[t]*rr[t];
      s = acc;
    }
    sv[m]=s; lmax=fmaxf(lmax,s);
  }
  red[tid]=lmax; __syncthreads();
  for (int k=128;k>0;k>>=1){ if (tid<k) red[tid]=fmaxf(red[tid],red[tid+k]); __syncthreads(); }
  float mx = red[0]; __syncthreads();
  float lsum=0.f;
  for (int m=tid;m<NN;m+=256){
    float e = (sv[m] > -1e29f) ? __expf(sv[m]-mx) : 0.f;
    sv[m]=e; lsum+=e;
  }
  red[tid]=lsum; __syncthreads();
  for (int k=128;k>0;k>>=1){ if (tid<k) red[tid]+=red[tid+k]; __syncthreads(); }
  float inv = 1.f/red[0];
  if (tid==0){
    int c=0;
    for (int m=0;m<NN;m++) if (sv[m]!=0.f){ ml[c]=m; wl[c]=sv[m]*inv; c++; }
    cnt=c;
  }
  __syncthreads();
  int K = cnt;
  { // z[c][t] = g[t]*(sum wr*x - sum wr*mu) + b[t], wr = w*rs  (sum_m w = 1)
    int c = tid>>2, tg = tid&3;     // 6 t's per thread
    float acc[6]={0,0,0,0,0,0};
    float s0 = 0.f;
    const float* mu_r = mu_a + (b*CC+c)*NN;
    const float* rs_r = rs_a + (b*CC+c)*NN;
    size_t xbase = (size_t)(b*CC+c)*NT;
    for (int k=0;k<K;k++){
      int m = ml[k];
      float wr = wl[k]*rs_r[m];
      s0 += wr*mu_r[m];
      size_t xm = xbase + m*TT + tg*6;
      for (int j=0;j<6;j++) acc[j] += wr*xload(x, xm+j, f);
    }
    for (int j=0;j<6;j++){
      int t = tg*6+j;
      z[c*TT+t] = gs[t]*(acc[j]-s0) + bs[t];
    }
  }
  __syncthreads();
  { // out[128+o] = Gs[o][:] @ z
    int o = tid>>2, tg = tid&3;
    float acc[6]={0,0,0,0,0,0};
    for (int c=0;c<CC;c++){
      float gwv = Gs[o*CC+c];
      const float* zr = &z[c*TT + tg*6];
      for (int j=0;j<6;j++) acc[j] += gwv*zr[j];
    }
    size_t base = ((size_t)b*CO + 128 + o)*NT + n*TT + tg*6;
    for (int j=0;j<6;j++)
      ostore(out, base+j, acc[j], f);
  }
}

// ---- 9. t-branch fused in LDS: att_t apply -> conv(d=1) -> conv(d=2); rows 64..127
__global__ __launch_bounds__(256) void k_tbranch(const void* __restrict__ x, const int* flagp,
    const float* __restrict__ mu_a, const float* __restrict__ rs_a,
    const float* __restrict__ W, const float* __restrict__ attt,
    void* __restrict__ out) {
  int chunk = blockIdx.x, b = blockIdx.y, tid = threadIdx.x;
  int f = *flagp;
  int n0 = chunk*4;
  const float* lng = W + OFF_ln_g;
  const float* lnb = W + OFF_ln_b;
  const float* W0  = W + OFF_tc_W0;
  const float* b0  = W + OFF_tc_b0;
  const float* W1  = W + OFF_tc_W1;
  const float* b1  = W + OFF_tc_b1;
  __shared__ float hs[CC*4*TT];   // [c][i][t]; later holds y0 [o][i][t]
  __shared__ float tmp[CC*4*TT];  // [c][i][t]
  __shared__ float at[TT*TT];
  for (int e=tid;e<CC*4*TT;e+=256){
    int c=e/(4*TT), rem=e%(4*TT), i=rem/TT, t=rem%TT;
    int n=n0+i;
    float hv=0.f;
    if (n<NN){
      int row=(b*CC+c)*NN+n;
      hv = (xload(x,(size_t)row*TT+t,f) - mu_a[row]) * rs_a[row] * lng[t] + lnb[t];
    }
    hs[e] = hv;
  }
  for (int e=tid;e<TT*TT;e+=256) at[e]=attt[b*TT*TT+e];
  __syncthreads();
  { // tmp[c][i][t] = sum_s att[t][s]*hs[c][i][s]
    int c = tid>>2, i = tid&3;
    float r[TT];
    for (int s=0;s<TT;s++) r[s]=hs[(c*4+i)*TT+s];
    for (int t=0;t<TT;t++){
      float acc=0.f;
      for (int s=0;s<TT;s++) acc += at[t*TT+s]*r[s];
      tmp[(c*4+i)*TT+t]=acc;
    }
  }
  __syncthreads();
  { // y0[o][i][t] = b0 + sum_c W0a*tmp[t-1] + W0b*tmp[t]  (into hs)
    int o = tid>>2, i = tid&3;
    float acc[TT];
    float bb = b0[o];
    for (int t=0;t<TT;t++) acc[t]=bb;
    for (int c=0;c<CC;c++){
      float wa = W0[(o*CC+c)*2], wb = W0[(o*CC+c)*2+1];
      const float* row = &tmp[(c*4+i)*TT];
      acc[0] += wb*row[0];
      for (int t=1;t<TT;t++) acc[t] += wa*row[t-1] + wb*row[t];
    }
    __syncthreads();
    for (int t=0;t<TT;t++) hs[(o*4+i)*TT+t]=acc[t];
  }
  __syncthreads();
  { // y1[o2][i][t] = b1 + sum_o W1a*y0[t-2] + W1b*y0[t]
    int o2 = tid>>2, i = tid&3;
    int n = n0+i;
    float acc[TT];
    float bb = b1[o2];
    for (int t=0;t<TT;t++) acc[t]=bb;
    for (int o=0;o<CC;o++){
      float wa = W1[(o2*CC+o)*2], wb = W1[(o2*CC+o)*2+1];
      const float* row = &hs[(o*4+i)*TT];
      acc[0] += wb*row[0];
      acc[1] += wb*row[1];
      for (int t=2;t<TT;t++) acc[t] += wa*row[t-2] + wb*row[t];
    }
    if (n<NN){
      for (int t=0;t<TT;t++)
        ostore(out, (((size_t)b*CO + 64 + o2)*NN + n)*TT + t, acc[t], f);
    }
  }
}

// ---- 10. final: out = relu(out + res_W@x + res_b)
__global__ __launch_bounds__(256) void k_res_final(const void* __restrict__ x, const int* flagp,
    const float* __restrict__ W, void* __restrict__ out) {
  int jt=blockIdx.x, ot=blockIdx.y, b=blockIdx.z; int tid=threadIdx.x;
  int f = *flagp;
  int j0=jt*64, o0=ot*64;
  const float* resW = W + OFF_res_W;
  const float* resb = W + OFF_res_b;
  __shared__ float Ws[CC*64];   // [c][o]
  __shared__ float Xs[CC*64];   // [c][j]
  for (int e=tid;e<CC*64;e+=256){
    int o=e&63, c=e>>6;
    Ws[e] = resW[(o0+o)*CC + c];
  }
  for (int e=tid;e<CC*64;e+=256){
    int c=e>>6, j=e&63; int jj=j0+j;
    Xs[e] = (jj<NT) ? xload(x, (size_t)(b*CC+c)*NT + jj, f) : 0.f;
  }
  __syncthreads();
  int ti=tid&15, tj=tid>>4;
  float acc[4][4]={};
  for (int k=0;k<CC;k++){
    float4 a4=*(const float4*)&Ws[k*64+ti*4];
    float4 b4=*(const float4*)&Xs[k*64+tj*4];
    float av[4]={a4.x,a4.y,a4.z,a4.w};
    float bv[4]={b4.x,b4.y,b4.z,b4.w};
    for (int i=0;i<4;i++)
      for (int j=0;j<4;j++) acc[i][j]+=av[i]*bv[j];
  }
  for (int i=0;i<4;i++){
    int o=o0+ti*4+i; float bias=resb[o];
    for (int j=0;j<4;j++){
      int jj=j0+tj*4+j;
      if (jj<NT){
        size_t idx=((size_t)b*CO+o)*NT+jj;
        float v = acc[i][j] + bias + oload(out, idx, f);
        ostore(out, idx, fmaxf(v,0.f), f);
      }
    }
  }
}

extern "C" void kernel_launch(void* const* d_in, const int* in_sizes, int n_in,
                              void* d_out, int out_size, void* d_ws, size_t ws_size,
                              hipStream_t stream) {
  const void* x     = d_in[0];
  const int*  adj   = (const int*)d_in[1];
  void* out = d_out;

  float* p = (float*)d_ws;
  int*   flagp = (int*)p; p += 4;                    // 16B for flag
  float* Wf  = p; p += W_TOTAL;                      // fp32 weight arena
  float* mu_a = p; p += (size_t)BB*CC*NN;
  float* rs_a = p; p += (size_t)BB*CC*NN;
  float* xw1c = p; p += (size_t)BB*CC*NN;
  float* xw1g = p; p += (size_t)BB*CC*NN;
  float* xw1t = p; p += (size_t)BB*CC*TT;
  float* lhsc = p; p += (size_t)BB*CC*TT;
  float* rhsc = p; p += (size_t)BB*CC*TT;
  float* rhst = p; p += (size_t)BB*NN*TT;
  float* rhsg = p; p += (size_t)BB*NN*TT;
  float* lhsg = p; p += (size_t)BB*NN*TT;
  float* lhst = p; p += (size_t)BB*TT*NN;
  float* attt = p; p += (size_t)BB*TT*TT;
  float* Mc   = p; p += (size_t)BB*CC*CC;
  // ~18.2 MB total

  k_probe<<<dim3(1), dim3(256), 0, stream>>>(d_in[2], flagp);
  k_cvt_w<<<dim3((W_TOTAL+255)/256), dim3(256), 0, stream>>>(
      d_in[2], d_in[3], d_in[4], d_in[5], d_in[6], d_in[7], d_in[8], d_in[9],
      d_in[10], d_in[11], d_in[12], d_in[13], d_in[14], d_in[15], d_in[16],
      d_in[17], d_in[18], d_in[19], d_in[20], d_in[21], flagp, Wf);
  int total_out = BB*CO*NT;
  k_fill<<<dim3((total_out+255)/256), dim3(256), 0, stream>>>(out, total_out, flagp);
  k_ln<<<dim3((BB*CC*NN+255)/256), dim3(256), 0, stream>>>(x, flagp, Wf, mu_a, rs_a, xw1c, xw1g);
  k_prep_ct<<<dim3((BB*CC*TT+255)/256), dim3(256), 0, stream>>>(x, flagp, mu_a, rs_a, Wf, xw1c, lhsc, rhsc, xw1t);
  k_prep_bn<<<dim3((BB*NN*TT+255)/256), dim3(256), 0, stream>>>(x, flagp, mu_a, rs_a, Wf, xw1g, rhst, rhsg, lhsg);
  k_lhs_t<<<dim3((BB*TT*NN+255)/256), dim3(256), 0, stream>>>(xw1t, Wf, lhst);
  k_att_c<<<dim3(BB), dim3(256), 0, stream>>>(lhsc, rhsc, Wf, Mc);
  k_att_t<<<dim3(BB), dim3(256), 0, stream>>>(lhst, rhst, attt);
  k_cmix<<<dim3((NT+63)/64, BB), dim3(256), 0, stream>>>(Mc, x, flagp, mu_a, rs_a, Wf, out);
  k_graph<<<dim3(NN, BB), dim3(256), 0, stream>>>(lhsg, rhsg, adj, x, flagp, mu_a, rs_a, Wf, out);
  k_tbranch<<<dim3((NN+3)/4, BB), dim3(256), 0, stream>>>(x, flagp, mu_a, rs_a, Wf, attt, out);
  k_res_final<<<dim3((NT+63)/64, 3, BB), dim3(256), 0, stream>>>(x, flagp, Wf, out);
}

// Round 5
// 1401.252 us; speedup vs baseline: 3.6172x; 3.6172x over previous
//
#include <hip/hip_runtime.h>
#include <hip/hip_bf16.h>

#define BB 32
#define CC 64
#define NN 307
#define TT 24
#define CO 192
#define NT (NN*TT)   // 7368
#define GO 1536      // CC*TT, hg row length

using bf16 = __hip_bfloat16;

// fp32 weight-arena offsets (element = float)
#define OFF_ln_g   0
#define OFF_ln_b   24
#define OFF_res_W  48
#define OFF_res_b  12336
#define OFF_ca_W1  12528
#define OFF_ca_W2  12552
#define OFF_ca_W3  19920
#define OFF_cc_W   20227
#define OFF_cc_b   24323
#define OFF_ta_W1  24387
#define OFF_ta_W2  24694
#define OFF_ta_W3  44342
#define OFF_tc_W0  44406
#define OFF_tc_b0  52598
#define OFF_tc_W1  52662
#define OFF_tc_b1  60854
#define OFF_ga_W1  60918
#define OFF_ga_W2  60942
#define OFF_ga_W3  62478
#define OFF_g_W    62542
#define W_TOTAL    66638

__device__ __forceinline__ float xload(const void* p, size_t i, int f) {
  return f ? ((const float*)p)[i] : __bfloat162float(((const bf16*)p)[i]);
}
__device__ __forceinline__ void ostore(void* p, size_t i, float v, int f) {
  if (f) ((float*)p)[i] = v; else ((bf16*)p)[i] = __float2bfloat16(v);
}
__device__ __forceinline__ float oload(const void* p, size_t i, int f) {
  return f ? ((const float*)p)[i] : __bfloat162float(((const bf16*)p)[i]);
}

__global__ void MEAM_44787918963464_kernel() {}

// ---- 0a. probe input float dtype from ln_g (all ones)
__global__ __launch_bounds__(256) void k_probe(const void* lng_raw, int* flag) {
  if (threadIdx.x == 0 && blockIdx.x == 0) {
    unsigned w = *(const unsigned*)lng_raw;
    *flag = (w == 0x3F800000u) ? 1 : 0;   // 1 = float32 inputs, 0 = bf16
  }
}

// ---- 0b. convert all small weights to fp32 arena
__global__ __launch_bounds__(256) void k_cvt_w(
    const void* p0, const void* p1, const void* p2, const void* p3,
    const void* p4, const void* p5, const void* p6, const void* p7,
    const void* p8, const void* p9, const void* p10, const void* p11,
    const void* p12, const void* p13, const void* p14, const void* p15,
    const void* p16, const void* p17, const void* p18, const void* p19,
    const int* flagp, float* dst) {
  int i = blockIdx.x*256 + threadIdx.x;
  if (i >= W_TOTAL) return;
  const void* ps[20] = {p0,p1,p2,p3,p4,p5,p6,p7,p8,p9,p10,p11,p12,p13,p14,p15,p16,p17,p18,p19};
  const int sz[20] = {24,24,12288,192,24,7368,307,4096,64,307,19648,64,8192,64,8192,64,24,1536,64,4096};
  int f = *flagp;
  int s = 0, base = 0;
  while (i >= base + sz[s]) { base += sz[s]; s++; }
  dst[i] = f ? ((const float*)ps[s])[i-base]
             : __bfloat162float(((const bf16*)ps[s])[i-base]);
}

// ---- 1. LN stats per row (b,c,n)
__global__ __launch_bounds__(256) void k_ln(const void* __restrict__ x, const int* flagp,
    const float* __restrict__ W,
    float* __restrict__ mu_o, float* __restrict__ rs_o,
    float* __restrict__ xw1c, float* __restrict__ xw1g) {
  int r = blockIdx.x*256 + threadIdx.x;     // (b*C+c)*N + n
  if (r >= BB*CC*NN) return;
  int f = *flagp;
  const float* lng  = W + OFF_ln_g;
  const float* lnb  = W + OFF_ln_b;
  const float* caW1 = W + OFF_ca_W1;
  const float* gaW1 = W + OFF_ga_W1;
  float v[TT];
  float mu = 0.f;
  for (int t=0;t<TT;t++){ v[t] = xload(x, (size_t)r*TT+t, f); mu += v[t]; }
  mu *= (1.f/TT);
  float var = 0.f;
  for (int t=0;t<TT;t++){ float d=v[t]-mu; var += d*d; }
  var *= (1.f/TT);
  float rs = rsqrtf(var + 1e-5f);
  float s1=0.f, s2=0.f;
  for (int t=0;t<TT;t++){
    float hv = (v[t]-mu)*rs*lng[t] + lnb[t];
    s1 += hv*caW1[t];
    s2 += hv*gaW1[t];
  }
  mu_o[r]=mu; rs_o[r]=rs; xw1c[r]=s1; xw1g[r]=s2;
}

// ---- 2. per (b,c,t): lhs_c, rhs_c, xW1_t (reduce over n)
__global__ __launch_bounds__(256) void k_prep_ct(const void* __restrict__ x, const int* flagp,
    const float* __restrict__ mu_a, const float* __restrict__ rs_a,
    const float* __restrict__ W, const float* __restrict__ xw1c,
    float* __restrict__ lhsc, float* __restrict__ rhsc, float* __restrict__ xw1t) {
  int i = blockIdx.x*256 + threadIdx.x;     // (b*C+c)*T + t
  if (i >= BB*CC*TT) return;
  int f = *flagp;
  const float* lng  = W + OFF_ln_g;
  const float* lnb  = W + OFF_ln_b;
  const float* caW2 = W + OFF_ca_W2;
  const float* caW3 = W + OFF_ca_W3;
  const float* taW1 = W + OFF_ta_W1;
  int t = i % TT; int bc = i / TT;
  float gt = lng[t], bt = lnb[t];
  float l=0.f, rr=0.f, xt=0.f;
  for (int n=0;n<NN;n++){
    int row = bc*NN + n;
    float hv = (xload(x, (size_t)row*TT+t, f) - mu_a[row]) * rs_a[row] * gt + bt;
    l  += xw1c[row]*caW2[n*TT+t];
    rr += caW3[n]*hv;
    xt += taW1[n]*hv;
  }
  lhsc[i]=l; rhsc[i]=rr; xw1t[i]=xt;
}

// ---- 3. per (b,n,t): rhs_t, rhs_g, lhs_g (reduce over c)
__global__ __launch_bounds__(256) void k_prep_bn(const void* __restrict__ x, const int* flagp,
    const float* __restrict__ mu_a, const float* __restrict__ rs_a,
    const float* __restrict__ W, const float* __restrict__ xw1g,
    float* __restrict__ rhst, float* __restrict__ rhsg, float* __restrict__ lhsg) {
  int i = blockIdx.x*256 + threadIdx.x;     // (b*N+n)*T + t
  if (i >= BB*NN*TT) return;
  int f = *flagp;
  const float* lng  = W + OFF_ln_g;
  const float* lnb  = W + OFF_ln_b;
  const float* taW3 = W + OFF_ta_W3;
  const float* gaW3 = W + OFF_ga_W3;
  const float* gaW2 = W + OFF_ga_W2;
  int t = i % TT; int n = (i/TT)%NN; int b = i/(NN*TT);
  float gt = lng[t], bt = lnb[t];
  float a=0.f,c2=0.f,d=0.f;
  for (int c=0;c<CC;c++){
    int row = (b*CC+c)*NN + n;
    float hv = (xload(x, (size_t)row*TT+t, f) - mu_a[row]) * rs_a[row] * gt + bt;
    a  += taW3[c]*hv;
    c2 += gaW3[c]*hv;
    d  += xw1g[row]*gaW2[c*TT+t];
  }
  rhst[i]=a; rhsg[i]=c2; lhsg[i]=d;
}

// ---- 4. lhs_t[b,t,n] = sum_c xW1_t[b,c,t]*taW2[c,n]
__global__ __launch_bounds__(256) void k_lhs_t(const float* __restrict__ xw1t,
    const float* __restrict__ W, float* __restrict__ lhst) {
  int i = blockIdx.x*256 + threadIdx.x;     // (b*T+t)*N + n
  if (i >= BB*TT*NN) return;
  const float* taW2 = W + OFF_ta_W2;
  int n = i % NN; int t = (i/NN)%TT; int b = i/(TT*NN);
  float acc=0.f;
  for (int c=0;c<CC;c++)
    acc += xw1t[(b*CC+c)*TT+t]*taW2[c*NN+n];
  lhst[i]=acc;
}

// ---- 5. channel attention softmax folded with cc_W -> Mc[o][d]
__global__ __launch_bounds__(256) void k_att_c(const float* __restrict__ lhsc,
    const float* __restrict__ rhsc, const float* __restrict__ W,
    float* __restrict__ Mc) {
  int b = blockIdx.x; int tid = threadIdx.x;
  const float* ccW = W + OFF_cc_W;
  __shared__ float lc[CC*TT], rc[CC*TT], sc[CC*(CC+1)];
  for (int e=tid;e<CC*TT;e+=256){
    lc[e]=lhsc[b*CC*TT+e];
    rc[e]=rhsc[b*CC*TT+e];
  }
  __syncthreads();
  for (int e=tid;e<CC*CC;e+=256){
    int c=e>>6, d=e&63; float s=0.f;
    for (int t=0;t<TT;t++) s += lc[c*TT+t]*rc[d*TT+t];
    sc[c*(CC+1)+d]=s;
  }
  __syncthreads();
  if (tid<CC){
    float mx=-1e30f;
    for (int d=0;d<CC;d++) mx=fmaxf(mx, sc[tid*(CC+1)+d]);
    float sum=0.f;
    for (int d=0;d<CC;d++){ float e2=__expf(sc[tid*(CC+1)+d]-mx); sc[tid*(CC+1)+d]=e2; sum+=e2; }
    float inv=1.f/sum;
    for (int d=0;d<CC;d++) sc[tid*(CC+1)+d]*=inv;
  }
  __syncthreads();
  for (int e=tid;e<CC*CC;e+=256){
    int o=e>>6, d=e&63; float acc=0.f;
    for (int c=0;c<CC;c++) acc += ccW[o*CC+c]*sc[c*(CC+1)+d];
    Mc[b*CC*CC+e]=acc;
  }
}

// ---- 6. temporal attention 24x24 softmax
__global__ __launch_bounds__(256) void k_att_t(const float* __restrict__ lhst,
    const float* __restrict__ rhst, float* __restrict__ attt) {
  int b=blockIdx.x, tid=threadIdx.x;
  __shared__ float sc[TT*TT];
  for (int e=tid;e<TT*TT;e+=256){
    int t=e/TT, s=e%TT;
    float acc=0.f;
    for (int n=0;n<NN;n++)
      acc += lhst[(b*TT+t)*NN+n]*rhst[(b*NN+n)*TT+s];
    sc[e]=acc;
  }
  __syncthreads();
  if (tid < TT){
    float mx=-1e30f;
    for (int s=0;s<TT;s++) mx=fmaxf(mx,sc[tid*TT+s]);
    float sum=0.f;
    for (int s=0;s<TT;s++){ float e=__expf(sc[tid*TT+s]-mx); sc[tid*TT+s]=e; sum+=e; }
    float inv=1.f/sum;
    for (int s=0;s<TT;s++) attt[b*TT*TT + tid*TT + s]=sc[tid*TT+s]*inv;
  }
}

// ---- 7a. graph attention -> dense attg[b][n][m] (fp32)
__global__ __launch_bounds__(256) void k_att_g(const float* __restrict__ lhsg,
    const float* __restrict__ rhsg, const int* __restrict__ adj,
    float* __restrict__ attg) {
  int n = blockIdx.x, b = blockIdx.y, tid = threadIdx.x;
  __shared__ float ls[TT];
  __shared__ float sv[NN];
  __shared__ float red[256];
  if (tid < TT) ls[tid] = lhsg[(b*NN+n)*TT + tid];
  __syncthreads();
  float lmax = -1e30f;
  for (int m=tid;m<NN;m+=256){
    float s = -1e30f;
    if (adj[n*NN+m] > 0){
      const float* rr = rhsg + ((size_t)b*NN+m)*TT;
      float acc=0.f;
      for (int t=0;t<TT;t++) acc += ls[t]*rr[t];
      s = acc;
    }
    sv[m]=s; lmax=fmaxf(lmax,s);
  }
  red[tid]=lmax; __syncthreads();
  for (int k=128;k>0;k>>=1){ if (tid<k) red[tid]=fmaxf(red[tid],red[tid+k]); __syncthreads(); }
  float mx = red[0]; __syncthreads();
  float lsum=0.f;
  for (int m=tid;m<NN;m+=256){
    float e = (sv[m] > -1e29f) ? __expf(sv[m]-mx) : 0.f;
    sv[m]=e; lsum+=e;
  }
  red[tid]=lsum; __syncthreads();
  for (int k=128;k>0;k>>=1){ if (tid<k) red[tid]+=red[tid+k]; __syncthreads(); }
  float inv = 1.f/red[0];
  for (int m=tid;m<NN;m+=256)
    attg[((size_t)b*NN+n)*NN+m] = sv[m]*inv;
}

// ---- 7b. fused channel-mix per (b,n): stacked [Mc;gW] (128x64) @ h[c][t]
//   rows 0..63  -> out c-branch (+ cc_b)
//   rows 64..127-> hg[b][n][(o,t)] bf16 (GEMM B operand)
__global__ __launch_bounds__(256) void k_hgc(const float* __restrict__ Mc,
    const void* __restrict__ x, const int* flagp,
    const float* __restrict__ mu_a, const float* __restrict__ rs_a,
    const float* __restrict__ W, bf16* __restrict__ hg,
    void* __restrict__ out) {
  int n = blockIdx.x, b = blockIdx.y, tid = threadIdx.x;
  int f = *flagp;
  const float* lng = W + OFF_ln_g;
  const float* lnb = W + OFF_ln_b;
  const float* ccb = W + OFF_cc_b;
  const float* gW  = W + OFF_g_W;
  __shared__ float Ss[128*65];   // padded rows: [row][c], row<64 = Mc, else gW
  __shared__ float Hs[CC*TT];    // [c][t]
  for (int e=tid;e<128*64;e+=256){
    int row=e>>6, c=e&63;
    Ss[row*65+c] = (row<64) ? Mc[b*CC*CC + row*CC + c] : gW[(row-64)*CC + c];
  }
  for (int e=tid;e<CC*TT;e+=256){
    int c=e/TT, t=e%TT;
    int r = (b*CC+c)*NN + n;
    Hs[e] = (xload(x, (size_t)(b*CC+c)*NT + n*TT + t, f) - mu_a[r]) * rs_a[r] * lng[t] + lnb[t];
  }
  __syncthreads();
  int o = tid>>1, half = tid&1;     // o in [0,128), 12 t's per thread
  float acc[12] = {};
  const float* hb = &Hs[half*12];
  for (int c=0;c<CC;c++){
    float s = Ss[o*65+c];
    const float* hr = hb + c*TT;
    #pragma unroll
    for (int j=0;j<12;j++) acc[j] += s*hr[j];
  }
  if (o < 64){
    float bias = ccb[o];
    size_t base = ((size_t)b*CO + o)*NT + n*TT + half*12;
    for (int j=0;j<12;j++) ostore(out, base+j, acc[j]+bias, f);
  } else {
    int op = o-64;
    size_t base = ((size_t)b*NN + n)*GO + op*TT + half*12;
    for (int j=0;j<12;j++) hg[base+j] = __float2bfloat16(acc[j]);
  }
}

// ---- 7c. graph GEMM per b: C[n][(o,t)] = sum_m attg[n][m] * hg[m][(o,t)]
__global__ __launch_bounds__(256) void k_gemm_g(const float* __restrict__ attg,
    const bf16* __restrict__ hg, const int* flagp, void* __restrict__ out) {
  int jt = blockIdx.x, nt = blockIdx.y, b = blockIdx.z;
  int tid = threadIdx.x;
  int f = *flagp;
  int n0 = nt*64, j0 = jt*64;
  __shared__ float As[16*68];    // [k][n], padded
  __shared__ float Bs[16*64];    // [k][j]
  float acc[4][4] = {};
  int ti = tid & 15, tj = tid >> 4;
  const float* Ab = attg + (size_t)b*NN*NN;
  const bf16*  Bb = hg + (size_t)b*NN*GO;
  for (int m0=0;m0<NN;m0+=16){
    for (int e=tid;e<1024;e+=256){
      int r=e>>4, k=e&15;
      int n=n0+r, mm=m0+k;
      As[k*68+r] = (n<NN && mm<NN) ? Ab[(size_t)n*NN+mm] : 0.f;
    }
    for (int e=tid;e<1024;e+=256){
      int k=e>>6, j=e&63;
      int mm=m0+k;
      Bs[k*64+j] = (mm<NN) ? __bfloat162float(Bb[(size_t)mm*GO + j0 + j]) : 0.f;
    }
    __syncthreads();
    #pragma unroll
    for (int k=0;k<16;k++){
      float4 a4 = *(const float4*)&As[k*68+ti*4];
      float4 b4 = *(const float4*)&Bs[k*64+tj*4];
      float av[4]={a4.x,a4.y,a4.z,a4.w};
      float bv[4]={b4.x,b4.y,b4.z,b4.w};
      #pragma unroll
      for (int i=0;i<4;i++)
        #pragma unroll
        for (int j=0;j<4;j++) acc[i][j] += av[i]*bv[j];
    }
    __syncthreads();
  }
  #pragma unroll
  for (int i=0;i<4;i++){
    int n = n0 + ti*4 + i;
    if (n >= NN) continue;
    #pragma unroll
    for (int j=0;j<4;j++){
      int jj = j0 + tj*4 + j;
      int o = jj/TT, t2 = jj%TT;
      ostore(out, (((size_t)b*CO + 128 + o)*NT + n*TT + t2), acc[i][j], f);
    }
  }
}

// ---- 8f. FALLBACK c-branch (round-4 k_cmix)
__global__ __launch_bounds__(256) void k_cmix(const float* __restrict__ Mc,
    const void* __restrict__ x, const int* flagp,
    const float* __restrict__ mu_a, const float* __restrict__ rs_a,
    const float* __restrict__ W, void* __restrict__ out) {
  int jt=blockIdx.x, b=blockIdx.y, tid=threadIdx.x;
  int f = *flagp;
  int j0=jt*64;
  const float* lng = W + OFF_ln_g;
  const float* lnb = W + OFF_ln_b;
  const float* ccb = W + OFF_cc_b;
  __shared__ float Ms[CC*64];
  __shared__ float Hs[CC*64];
  for (int e=tid;e<CC*64;e+=256){
    int o=e&63, d=e>>6;
    Ms[e]=Mc[b*CC*CC + o*CC + d];
  }
  for (int e=tid;e<CC*64;e+=256){
    int d=e>>6, j=e&63; int jj=j0+j;
    float hv = 0.f;
    if (jj<NT){
      int n = jj/TT, t = jj%TT;
      int row = (b*CC+d)*NN + n;
      hv = (xload(x, (size_t)(b*CC+d)*NT + jj, f) - mu_a[row]) * rs_a[row] * lng[t] + lnb[t];
    }
    Hs[e]=hv;
  }
  __syncthreads();
  int ti=tid&15, tj=tid>>4;
  float acc[4][4]={};
  for (int d=0;d<CC;d++){
    float4 a4=*(const float4*)&Ms[d*64+ti*4];
    float4 b4=*(const float4*)&Hs[d*64+tj*4];
    float av[4]={a4.x,a4.y,a4.z,a4.w};
    float bv[4]={b4.x,b4.y,b4.z,b4.w};
    for (int i=0;i<4;i++)
      for (int j=0;j<4;j++) acc[i][j]+=av[i]*bv[j];
  }
  for (int i=0;i<4;i++){
    int o=ti*4+i; float bias=ccb[o];
    for (int j=0;j<4;j++){
      int jj=j0+tj*4+j;
      if (jj<NT)
        ostore(out, ((size_t)b*CO+o)*NT+jj, acc[i][j]+bias, f);
    }
  }
}

// ---- 8g. FALLBACK fused g-branch (round-4 k_graph)
__global__ __launch_bounds__(256) void k_graph(const float* __restrict__ lhsg,
    const float* __restrict__ rhsg, const int* __restrict__ adj,
    const void* __restrict__ x, const int* flagp,
    const float* __restrict__ mu_a, const float* __restrict__ rs_a,
    const float* __restrict__ W, void* __restrict__ out) {
  int n = blockIdx.x, b = blockIdx.y, tid = threadIdx.x;
  int f = *flagp;
  const float* lng = W + OFF_ln_g;
  const float* lnb = W + OFF_ln_b;
  const float* gW  = W + OFF_g_W;
  __shared__ float ls[TT];
  __shared__ float sv[NN];
  __shared__ float red[256];
  __shared__ float wl[NN];
  __shared__ int   ml[NN];
  __shared__ int   cnt;
  __shared__ float z[CC*TT];
  __shared__ float Gs[CC*CC];
  __shared__ float gs[TT], bs[TT];
  if (tid < TT){
    ls[tid] = lhsg[(b*NN+n)*TT + tid];
    gs[tid] = lng[tid]; bs[tid] = lnb[tid];
  }
  for (int e=tid;e<CC*CC;e+=256) Gs[e]=gW[e];
  __syncthreads();
  float lmax = -1e30f;
  for (int m=tid;m<NN;m+=256){
    float s = -1e30f;
    if (adj[n*NN+m] > 0){
      const float* rr = rhsg + ((size_t)b*NN+m)*TT;
      float acc=0.f;
      for (int t=0;t<TT;t++) acc += ls[t]*rr[t];
      s = acc;
    }
    sv[m]=s; lmax=fmaxf(lmax,s);
  }
  red[tid]=lmax; __syncthreads();
  for (int k=128;k>0;k>>=1){ if (tid<k) red[tid]=fmaxf(red[tid],red[tid+k]); __syncthreads(); }
  float mx = red[0]; __syncthreads();
  float lsum=0.f;
  for (int m=tid;m<NN;m+=256){
    float e = (sv[m] > -1e29f) ? __expf(sv[m]-mx) : 0.f;
    sv[m]=e; lsum+=e;
  }
  red[tid]=lsum; __syncthreads();
  for (int k=128;k>0;k>>=1){ if (tid<k) red[tid]+=red[tid+k]; __syncthreads(); }
  float inv = 1.f/red[0];
  if (tid==0){
    int c=0;
    for (int m=0;m<NN;m++) if (sv[m]!=0.f){ ml[c]=m; wl[c]=sv[m]*inv; c++; }
    cnt=c;
  }
  __syncthreads();
  int K = cnt;
  {
    int c = tid>>2, tg = tid&3;
    float acc[6]={0,0,0,0,0,0};
    float s0 = 0.f;
    const float* mu_r = mu_a + (b*CC+c)*NN;
    const float* rs_r = rs_a + (b*CC+c)*NN;
    size_t xbase = (size_t)(b*CC+c)*NT;
    for (int k=0;k<K;k++){
      int m = ml[k];
      float wr = wl[k]*rs_r[m];
      s0 += wr*mu_r[m];
      size_t xm = xbase + m*TT + tg*6;
      for (int j=0;j<6;j++) acc[j] += wr*xload(x, xm+j, f);
    }
    for (int j=0;j<6;j++){
      int t = tg*6+j;
      z[c*TT+t] = gs[t]*(acc[j]-s0) + bs[t];
    }
  }
  __syncthreads();
  {
    int o = tid>>2, tg = tid&3;
    float acc[6]={0,0,0,0,0,0};
    for (int c=0;c<CC;c++){
      float gwv = Gs[o*CC+c];
      const float* zr = &z[c*TT + tg*6];
      for (int j=0;j<6;j++) acc[j] += gwv*zr[j];
    }
    size_t base = ((size_t)b*CO + 128 + o)*NT + n*TT + tg*6;
    for (int j=0;j<6;j++)
      ostore(out, base+j, acc[j], f);
  }
}

// ---- 9. t-branch fused in LDS
__global__ __launch_bounds__(256) void k_tbranch(const void* __restrict__ x, const int* flagp,
    const float* __restrict__ mu_a, const float* __restrict__ rs_a,
    const float* __restrict__ W, const float* __restrict__ attt,
    void* __restrict__ out) {
  int chunk = blockIdx.x, b = blockIdx.y, tid = threadIdx.x;
  int f = *flagp;
  int n0 = chunk*4;
  const float* lng = W + OFF_ln_g;
  const float* lnb = W + OFF_ln_b;
  const float* W0  = W + OFF_tc_W0;
  const float* b0  = W + OFF_tc_b0;
  const float* W1  = W + OFF_tc_W1;
  const float* b1  = W + OFF_tc_b1;
  __shared__ float hs[CC*4*TT];
  __shared__ float tmp[CC*4*TT];
  __shared__ float at[TT*TT];
  for (int e=tid;e<CC*4*TT;e+=256){
    int c=e/(4*TT), rem=e%(4*TT), i=rem/TT, t=rem%TT;
    int n=n0+i;
    float hv=0.f;
    if (n<NN){
      int row=(b*CC+c)*NN+n;
      hv = (xload(x,(size_t)row*TT+t,f) - mu_a[row]) * rs_a[row] * lng[t] + lnb[t];
    }
    hs[e] = hv;
  }
  for (int e=tid;e<TT*TT;e+=256) at[e]=attt[b*TT*TT+e];
  __syncthreads();
  {
    int c = tid>>2, i = tid&3;
    float r[TT];
    for (int s=0;s<TT;s++) r[s]=hs[(c*4+i)*TT+s];
    for (int t=0;t<TT;t++){
      float acc=0.f;
      for (int s=0;s<TT;s++) acc += at[t*TT+s]*r[s];
      tmp[(c*4+i)*TT+t]=acc;
    }
  }
  __syncthreads();
  {
    int o = tid>>2, i = tid&3;
    float acc[TT];
    float bb = b0[o];
    for (int t=0;t<TT;t++) acc[t]=bb;
    for (int c=0;c<CC;c++){
      float wa = W0[(o*CC+c)*2], wb = W0[(o*CC+c)*2+1];
      const float* row = &tmp[(c*4+i)*TT];
      acc[0] += wb*row[0];
      for (int t=1;t<TT;t++) acc[t] += wa*row[t-1] + wb*row[t];
    }
    __syncthreads();
    for (int t=0;t<TT;t++) hs[(o*4+i)*TT+t]=acc[t];
  }
  __syncthreads();
  {
    int o2 = tid>>2, i = tid&3;
    int n = n0+i;
    float acc[TT];
    float bb = b1[o2];
    for (int t=0;t<TT;t++) acc[t]=bb;
    for (int o=0;o<CC;o++){
      float wa = W1[(o2*CC+o)*2], wb = W1[(o2*CC+o)*2+1];
      const float* row = &hs[(o*4+i)*TT];
      acc[0] += wb*row[0];
      acc[1] += wb*row[1];
      for (int t=2;t<TT;t++) acc[t] += wa*row[t-2] + wb*row[t];
    }
    if (n<NN){
      for (int t=0;t<TT;t++)
        ostore(out, (((size_t)b*CO + 64 + o2)*NN + n)*TT + t, acc[t], f);
    }
  }
}

// ---- 10. final: out = relu(out + res_W@x + res_b)
__global__ __launch_bounds__(256) void k_res_final(const void* __restrict__ x, const int* flagp,
    const float* __restrict__ W, void* __restrict__ out) {
  int jt=blockIdx.x, ot=blockIdx.y, b=blockIdx.z; int tid=threadIdx.x;
  int f = *flagp;
  int j0=jt*64, o0=ot*64;
  const float* resW = W + OFF_res_W;
  const float* resb = W + OFF_res_b;
  __shared__ float Ws[CC*64];
  __shared__ float Xs[CC*64];
  for (int e=tid;e<CC*64;e+=256){
    int o=e&63, c=e>>6;
    Ws[e] = resW[(o0+o)*CC + c];
  }
  for (int e=tid;e<CC*64;e+=256){
    int c=e>>6, j=e&63; int jj=j0+j;
    Xs[e] = (jj<NT) ? xload(x, (size_t)(b*CC+c)*NT + jj, f) : 0.f;
  }
  __syncthreads();
  int ti=tid&15, tj=tid>>4;
  float acc[4][4]={};
  for (int k=0;k<CC;k++){
    float4 a4=*(const float4*)&Ws[k*64+ti*4];
    float4 b4=*(const float4*)&Xs[k*64+tj*4];
    float av[4]={a4.x,a4.y,a4.z,a4.w};
    float bv[4]={b4.x,b4.y,b4.z,b4.w};
    for (int i=0;i<4;i++)
      for (int j=0;j<4;j++) acc[i][j]+=av[i]*bv[j];
  }
  for (int i=0;i<4;i++){
    int o=o0+ti*4+i; float bias=resb[o];
    for (int j=0;j<4;j++){
      int jj=j0+tj*4+j;
      if (jj<NT){
        size_t idx=((size_t)b*CO+o)*NT+jj;
        float v = acc[i][j] + bias + oload(out, idx, f);
        ostore(out, idx, fmaxf(v,0.f), f);
      }
    }
  }
}

extern "C" void kernel_launch(void* const* d_in, const int* in_sizes, int n_in,
                              void* d_out, int out_size, void* d_ws, size_t ws_size,
                              hipStream_t stream) {
  const void* x     = d_in[0];
  const int*  adj   = (const int*)d_in[1];
  void* out = d_out;

  float* p = (float*)d_ws;
  int*   flagp = (int*)p; p += 4;
  float* Wf  = p; p += W_TOTAL;
  float* mu_a = p; p += (size_t)BB*CC*NN;
  float* rs_a = p; p += (size_t)BB*CC*NN;
  float* xw1c = p; p += (size_t)BB*CC*NN;
  float* xw1g = p; p += (size_t)BB*CC*NN;
  float* xw1t = p; p += (size_t)BB*CC*TT;
  float* lhsc = p; p += (size_t)BB*CC*TT;
  float* rhsc = p; p += (size_t)BB*CC*TT;
  float* rhst = p; p += (size_t)BB*NN*TT;
  float* rhsg = p; p += (size_t)BB*NN*TT;
  float* lhsg = p; p += (size_t)BB*NN*TT;
  float* lhst = p; p += (size_t)BB*TT*NN;
  float* attt = p; p += (size_t)BB*TT*TT;
  float* Mc   = p; p += (size_t)BB*CC*CC;
  // GEMM-path extras:
  float* attg = p; p += (size_t)BB*NN*NN;          // 12.06 MB
  bf16*  hg   = (bf16*)p;                          // 30.2 MB
  size_t need = ((char*)(hg + (size_t)BB*NN*GO)) - (char*)d_ws;
  bool gemm_path = (ws_size >= need);

  k_probe<<<dim3(1), dim3(256), 0, stream>>>(d_in[2], flagp);
  k_cvt_w<<<dim3((W_TOTAL+255)/256), dim3(256), 0, stream>>>(
      d_in[2], d_in[3], d_in[4], d_in[5], d_in[6], d_in[7], d_in[8], d_in[9],
      d_in[10], d_in[11], d_in[12], d_in[13], d_in[14], d_in[15], d_in[16],
      d_in[17], d_in[18], d_in[19], d_in[20], d_in[21], flagp, Wf);
  k_ln<<<dim3((BB*CC*NN+255)/256), dim3(256), 0, stream>>>(x, flagp, Wf, mu_a, rs_a, xw1c, xw1g);
  k_prep_ct<<<dim3((BB*CC*TT+255)/256), dim3(256), 0, stream>>>(x, flagp, mu_a, rs_a, Wf, xw1c, lhsc, rhsc, xw1t);
  k_prep_bn<<<dim3((BB*NN*TT+255)/256), dim3(256), 0, stream>>>(x, flagp, mu_a, rs_a, Wf, xw1g, rhst, rhsg, lhsg);
  k_lhs_t<<<dim3((BB*TT*NN+255)/256), dim3(256), 0, stream>>>(xw1t, Wf, lhst);
  k_att_c<<<dim3(BB), dim3(256), 0, stream>>>(lhsc, rhsc, Wf, Mc);
  k_att_t<<<dim3(BB), dim3(256), 0, stream>>>(lhst, rhst, attt);
  if (gemm_path) {
    k_att_g<<<dim3(NN, BB), dim3(256), 0, stream>>>(lhsg, rhsg, adj, attg);
    k_hgc<<<dim3(NN, BB), dim3(256), 0, stream>>>(Mc, x, flagp, mu_a, rs_a, Wf, hg, out);
    k_gemm_g<<<dim3(GO/64, (NN+63)/64, BB), dim3(256), 0, stream>>>(attg, hg, flagp, out);
  } else {
    k_cmix<<<dim3((NT+63)/64, BB), dim3(256), 0, stream>>>(Mc, x, flagp, mu_a, rs_a, Wf, out);
    k_graph<<<dim3(NN, BB), dim3(256), 0, stream>>>(lhsg, rhsg, adj, x, flagp, mu_a, rs_a, Wf, out);
  }
  k_tbranch<<<dim3((NN+3)/4, BB), dim3(256), 0, stream>>>(x, flagp, mu_a, rs_a, Wf, attt, out);
  k_res_final<<<dim3((NT+63)/64, 3, BB), dim3(256), 0, stream>>>(x, flagp, Wf, out);
}